// Round 4
// baseline (198.333 us; speedup 1.0000x reference)
//
#include <hip/hip_runtime.h>
#include <cstddef>

#define SSM_N 64
#define SSM_H 256
#define SSM_B 8
#define SSM_L 1024
#define PADM  68    // row stride (floats); 272B rows, 16B-aligned
#define KTP   1040  // K_T row stride in floats

// 4x4 register-tile matmul piece: acc += A[4ti+ii][k] * B[k][4tj+jj], k=0..63.
// A,B row-major in LDS (stride PADM). Per-lane float4 row reads (full LDS BW).
__device__ __forceinline__ void mm_tile(const float* __restrict__ A,
                                        const float* __restrict__ B,
                                        int ti, int tj, float acc[4][4])
{
    #pragma unroll
    for (int kb = 0; kb < 16; ++kb) {
        float4 av[4], bv4[4];
        #pragma unroll
        for (int ii = 0; ii < 4; ++ii)
            av[ii] = *reinterpret_cast<const float4*>(A + (4*ti+ii)*PADM + 4*kb);
        #pragma unroll
        for (int kk = 0; kk < 4; ++kk)
            bv4[kk] = *reinterpret_cast<const float4*>(B + (4*kb+kk)*PADM + 4*tj);
        #pragma unroll
        for (int kk = 0; kk < 4; ++kk) {
            const float b0 = bv4[kk].x, b1 = bv4[kk].y, b2 = bv4[kk].z, b3 = bv4[kk].w;
            #pragma unroll
            for (int ii = 0; ii < 4; ++ii) {
                const float a = reinterpret_cast<const float*>(&av[ii])[kk];
                acc[ii][0] += a * b0; acc[ii][1] += a * b1;
                acc[ii][2] += a * b2; acc[ii][3] += a * b3;
            }
        }
    }
}

// One block per channel h. 256 threads = 16x16 grid (ti=tid&15, tj=tid>>4),
// each thread owns a 4x4 tile. Doubling ladder: E_k = Ab^(2^k), k=0..9.
// c_j (j<32) and x_m (m<32) built by log-doubling. ~16 barriers total.
__global__ __launch_bounds__(256) void ssm_prep_kernel(
    const float* __restrict__ As, const float* __restrict__ Bsin,
    const float* __restrict__ Csin, const float* __restrict__ logsteps,
    float* __restrict__ KTout)
{
    __shared__ __align__(16) float Ea[SSM_N * PADM];
    __shared__ __align__(16) float Eb[SSM_N * PADM];
    __shared__ __align__(16) float Cm[32 * PADM];   // c_j rows
    __shared__ __align__(16) float Xm[32 * PADM];   // x_m rows (x stored as row)
    __shared__ float bvs[64];

    const int h    = blockIdx.x;
    const int tid  = threadIdx.x;
    const int lane = tid & 63;
    const int q    = tid >> 6;
    const int ti   = tid & 15;
    const int tj   = tid >> 4;

    const float step = expf(logsteps[h]);
    const float s    = 0.5f * step;

    // early global loads for b and Cs (one value per lane of waves 0/1)
    float breg = 0.f, creg = 0.f;
    if (q == 0) breg = Bsin[h * SSM_N + lane];
    if (q == 1) creg = Csin[h * SSM_N + lane];

    // ---- load M = s*A into Ea (coalesced float4) ----
    #pragma unroll
    for (int r = 0; r < 4; ++r) {
        float4 v = *reinterpret_cast<const float4*>(As + (size_t)h * 4096 + 1024 * r + 4 * tid);
        const int i = 16 * r + tj;
        *reinterpret_cast<float4*>(Ea + i * PADM + 4 * ti) =
            make_float4(s * v.x, s * v.y, s * v.z, s * v.w);
    }
    if (q == 0) bvs[lane] = breg;
    __syncthreads();

    // ---- T = M*M + M -> Eb ----
    {
        float acc[4][4];
        #pragma unroll
        for (int ii = 0; ii < 4; ++ii) {
            float4 m4 = *reinterpret_cast<const float4*>(Ea + (4*ti+ii)*PADM + 4*tj);
            acc[ii][0] = m4.x; acc[ii][1] = m4.y; acc[ii][2] = m4.z; acc[ii][3] = m4.w;
        }
        mm_tile(Ea, Ea, ti, tj, acc);
        #pragma unroll
        for (int ii = 0; ii < 4; ++ii)
            *reinterpret_cast<float4*>(Eb + (4*ti+ii)*PADM + 4*tj) =
                make_float4(acc[ii][0], acc[ii][1], acc[ii][2], acc[ii][3]);
    }
    __syncthreads();

    // ---- S = M*T + M; E0 = I + 2S -> overwrite Eb (barrier between read & write) ----
    {
        float acc[4][4];
        #pragma unroll
        for (int ii = 0; ii < 4; ++ii) {
            float4 m4 = *reinterpret_cast<const float4*>(Ea + (4*ti+ii)*PADM + 4*tj);
            acc[ii][0] = m4.x; acc[ii][1] = m4.y; acc[ii][2] = m4.z; acc[ii][3] = m4.w;
        }
        mm_tile(Ea, Eb, ti, tj, acc);
        __syncthreads();   // all reads of Eb (=T) done before overwrite
        #pragma unroll
        for (int ii = 0; ii < 4; ++ii) {
            float4 w;
            w.x = 2.f*acc[ii][0] + ((4*ti+ii) == (4*tj+0) ? 1.f : 0.f);
            w.y = 2.f*acc[ii][1] + ((4*ti+ii) == (4*tj+1) ? 1.f : 0.f);
            w.z = 2.f*acc[ii][2] + ((4*ti+ii) == (4*tj+2) ? 1.f : 0.f);
            w.w = 2.f*acc[ii][3] + ((4*ti+ii) == (4*tj+3) ? 1.f : 0.f);
            *reinterpret_cast<float4*>(Eb + (4*ti+ii)*PADM + 4*tj) = w;
        }
    }
    if (q == 1) Cm[lane] = creg;       // c_0 = Cs
    __syncthreads();

    // ---- x_0 = Bb = s*(E0*b + b)  (wave 0; per-lane row read of E0) ----
    if (q == 0) {
        float accb = 0.f;
        #pragma unroll
        for (int r = 0; r < 16; ++r) {
            float4 e4 = *reinterpret_cast<const float4*>(Eb + lane * PADM + 4 * r);
            accb += e4.x * bvs[4*r] + e4.y * bvs[4*r+1] + e4.z * bvs[4*r+2] + e4.w * bvs[4*r+3];
        }
        Xm[lane] = s * (accb + bvs[lane]);
    }
    __syncthreads();

    // ---- c-doubling stages + squaring ladder: E0..E5 ----
    float* Ecur = Eb;
    float* Enext = Ea;
    #pragma unroll 1
    for (int k = 0; k < 5; ++k) {
        // c-stage k: rows [2^k, 2^{k+1}) = rows [0,2^k) * E_k
        const int rr = tid >> 4;
        if (rr < (1 << k)) {
            const float* crow = Cm + rr * PADM;
            float a0 = 0.f, a1 = 0.f, a2 = 0.f, a3 = 0.f;
            #pragma unroll
            for (int kb = 0; kb < 16; ++kb) {
                float4 c4 = *reinterpret_cast<const float4*>(crow + 4 * kb);
                #pragma unroll
                for (int kk = 0; kk < 4; ++kk) {
                    float4 e4 = *reinterpret_cast<const float4*>(Ecur + (4*kb+kk)*PADM + 4*ti);
                    const float cc = reinterpret_cast<const float*>(&c4)[kk];
                    a0 += cc * e4.x; a1 += cc * e4.y; a2 += cc * e4.z; a3 += cc * e4.w;
                }
            }
            *reinterpret_cast<float4*>(Cm + (rr + (1 << k)) * PADM + 4 * ti) =
                make_float4(a0, a1, a2, a3);
        }
        // squaring: E_{k+1} = E_k^2 -> Enext
        {
            float acc[4][4];
            #pragma unroll
            for (int ii = 0; ii < 4; ++ii)
                acc[ii][0] = acc[ii][1] = acc[ii][2] = acc[ii][3] = 0.f;
            mm_tile(Ecur, Ecur, ti, tj, acc);
            #pragma unroll
            for (int ii = 0; ii < 4; ++ii)
                *reinterpret_cast<float4*>(Enext + (4*ti+ii)*PADM + 4*tj) =
                    make_float4(acc[ii][0], acc[ii][1], acc[ii][2], acc[ii][3]);
        }
        __syncthreads();
        float* tmp = Ecur; Ecur = Enext; Enext = tmp;
    }

    // ---- x-doubling stages + squaring ladder: E5..E9 (Ecur = E5 = Ab^32) ----
    #pragma unroll 1
    for (int k = 0; k < 5; ++k) {
        const int mm_ = tid >> 4;
        if (mm_ < (1 << k)) {
            const float* xrow = Xm + mm_ * PADM;
            float a0 = 0.f, a1 = 0.f, a2 = 0.f, a3 = 0.f;
            #pragma unroll
            for (int kb = 0; kb < 16; ++kb) {
                float4 x4 = *reinterpret_cast<const float4*>(xrow + 4 * kb);
                float4 f0 = *reinterpret_cast<const float4*>(Ecur + (4*ti+0)*PADM + 4*kb);
                float4 f1 = *reinterpret_cast<const float4*>(Ecur + (4*ti+1)*PADM + 4*kb);
                float4 f2 = *reinterpret_cast<const float4*>(Ecur + (4*ti+2)*PADM + 4*kb);
                float4 f3 = *reinterpret_cast<const float4*>(Ecur + (4*ti+3)*PADM + 4*kb);
                a0 += f0.x*x4.x + f0.y*x4.y + f0.z*x4.z + f0.w*x4.w;
                a1 += f1.x*x4.x + f1.y*x4.y + f1.z*x4.z + f1.w*x4.w;
                a2 += f2.x*x4.x + f2.y*x4.y + f2.z*x4.z + f2.w*x4.w;
                a3 += f3.x*x4.x + f3.y*x4.y + f3.z*x4.z + f3.w*x4.w;
            }
            *reinterpret_cast<float4*>(Xm + (mm_ + (1 << k)) * PADM + 4 * ti) =
                make_float4(a0, a1, a2, a3);
        }
        if (k < 4) {
            float acc[4][4];
            #pragma unroll
            for (int ii = 0; ii < 4; ++ii)
                acc[ii][0] = acc[ii][1] = acc[ii][2] = acc[ii][3] = 0.f;
            mm_tile(Ecur, Ecur, ti, tj, acc);
            #pragma unroll
            for (int ii = 0; ii < 4; ++ii)
                *reinterpret_cast<float4*>(Enext + (4*ti+ii)*PADM + 4*tj) =
                    make_float4(acc[ii][0], acc[ii][1], acc[ii][2], acc[ii][3]);
        }
        __syncthreads();
        float* tmp = Ecur; Ecur = Enext; Enext = tmp;
    }

    // ---- KT[h][32m + j] = dot(c_j, x_m) ----
    #pragma unroll
    for (int r = 0; r < 4; ++r) {
        const int l = r * 256 + tid;
        const int m_ = l >> 5, j_ = l & 31;
        const float4* cr = reinterpret_cast<const float4*>(Cm + j_ * PADM);
        const float4* xr = reinterpret_cast<const float4*>(Xm + m_ * PADM);
        float sacc = 0.f;
        #pragma unroll
        for (int i = 0; i < 16; ++i) {
            const float4 c4 = cr[i], x4 = xr[i];
            sacc += c4.x * x4.x + c4.y * x4.y + c4.z * x4.z + c4.w * x4.w;
        }
        KTout[(size_t)h * KTP + l] = sacc;
    }
}

// KT (H x KTP, padded) -> K (L x H). 32x32 LDS tiles, coalesced both sides.
__global__ __launch_bounds__(256) void ssm_ktr_kernel(
    const float* __restrict__ KT, float* __restrict__ K)
{
    __shared__ float tile[32][33];
    const int l0 = (blockIdx.x & 31) * 32;
    const int h0 = (blockIdx.x >> 5) * 32;
    const int c  = threadIdx.x & 31;
    const int r0 = threadIdx.x >> 5;
    #pragma unroll
    for (int k = 0; k < 4; ++k)
        tile[r0 + 8 * k][c] = KT[(size_t)(h0 + r0 + 8 * k) * KTP + l0 + c];
    __syncthreads();
    #pragma unroll
    for (int k = 0; k < 4; ++k)
        K[(size_t)(l0 + r0 + 8 * k) * SSM_H + h0 + c] = tile[c][r0 + 8 * k];
}

// Causal conv: y[b,l,h] = sum_d K[d,h]*u[b,l-d,h] + Ds[h]*u[b,l,h].
// 128 threads (h-half), block = (b, pair p, hg). Tiles (p, 63-p) of 16 rows:
// uniform 66 chunks of 16 d-steps; 256 FMA per chunk vs 32 loads + 31 movs.
__global__ __launch_bounds__(128) void ssm_conv_kernel(
    const float* __restrict__ U, const float* __restrict__ Kk,
    const float* __restrict__ Ds, float* __restrict__ Y)
{
    const int tid = threadIdx.x;
    const int b   = blockIdx.x & 7;
    const int pp  = (blockIdx.x >> 3) & 31;
    const int hg  = blockIdx.x >> 8;
    const int h   = (hg << 7) + tid;
    const float dh = Ds[h];
    const float* Ub = U + (size_t)b * SSM_L * SSM_H + h;
    float* Yb = Y + (size_t)b * SSM_L * SSM_H + h;

    #pragma unroll
    for (int half = 0; half < 2; ++half) {
        const int t  = (half == 0) ? pp : (63 - pp);
        const int l0 = t << 4;
        float acc[16], win[31], kreg[16];
        #pragma unroll
        for (int i = 0; i < 16; ++i) acc[i] = 0.f;

        // win[j] = u[l0-15+j]; negative indices (only t=0) -> 0
        if (t == 0) {
            #pragma unroll
            for (int j = 0; j < 31; ++j)
                win[j] = (j >= 15) ? Ub[(j - 15) * SSM_H] : 0.f;
        } else {
            #pragma unroll
            for (int j = 0; j < 31; ++j)
                win[j] = Ub[(l0 - 15 + j) * SSM_H];
        }
        #pragma unroll
        for (int j = 0; j < 16; ++j) kreg[j] = Kk[j * SSM_H + h];

        // clean chunks c = 0..t-2 (both prefetches provably in range)
        const float* kp = Kk + 16 * SSM_H + h;
        const float* up = Ub + (l0 - 31) * SSM_H;
        #pragma unroll 1
        for (int c = 0; c < t - 1; ++c) {
            float kn[16], nw[16];
            #pragma unroll
            for (int j = 0; j < 16; ++j) kn[j] = kp[j * SSM_H];
            #pragma unroll
            for (int j = 0; j < 16; ++j) nw[j] = up[j * SSM_H];
            #pragma unroll
            for (int dd = 0; dd < 16; ++dd) {
                const float kv = kreg[dd];
                #pragma unroll
                for (int i = 0; i < 16; ++i) acc[i] += kv * win[15 + i - dd];
            }
            #pragma unroll
            for (int j = 30; j >= 16; --j) win[j] = win[j - 16];
            #pragma unroll
            for (int j = 0; j < 16; ++j) { win[j] = nw[j]; kreg[j] = kn[j]; }
            kp += 16 * SSM_H;
            up -= 16 * SSM_H;
        }

        // boundary chunk c = t-1: next window is zeros except u[0]
        if (t >= 1) {
            float kn[16];
            #pragma unroll
            for (int j = 0; j < 16; ++j) kn[j] = Kk[(16 * t + j) * SSM_H + h];
            const float uz = Ub[0];
            #pragma unroll
            for (int dd = 0; dd < 16; ++dd) {
                const float kv = kreg[dd];
                #pragma unroll
                for (int i = 0; i < 16; ++i) acc[i] += kv * win[15 + i - dd];
            }
            #pragma unroll
            for (int j = 30; j >= 16; --j) win[j] = win[j - 16];
            #pragma unroll
            for (int j = 0; j < 15; ++j) win[j] = 0.f;
            win[15] = uz;
            #pragma unroll
            for (int j = 0; j < 16; ++j) kreg[j] = kn[j];
        }

        // final chunk c = t: FMA only
        #pragma unroll
        for (int dd = 0; dd < 16; ++dd) {
            const float kv = kreg[dd];
            #pragma unroll
            for (int i = 0; i < 16; ++i) acc[i] += kv * win[15 + i - dd];
        }

        #pragma unroll
        for (int i = 0; i < 16; ++i)
            Yb[(l0 + i) * SSM_H] = acc[i] + dh * Ub[(l0 + i) * SSM_H];
    }
}

extern "C" void kernel_launch(void* const* d_in, const int* in_sizes, int n_in,
                              void* d_out, int out_size, void* d_ws, size_t ws_size,
                              hipStream_t stream)
{
    const float* inp    = (const float*)d_in[0];  // (B,L,H)
    const float* As     = (const float*)d_in[1];  // (H,N,N)
    const float* Bsin   = (const float*)d_in[2];  // (H,N,1)
    const float* Csin   = (const float*)d_in[3];  // (H,1,N)
    const float* Dsin   = (const float*)d_in[4];  // (H,)
    const float* lsteps = (const float*)d_in[5];  // (H,)
    float* Y    = (float*)d_out;                  // (B,L,H)
    // KT staged in d_out head (consumed by ktr before conv overwrites with Y);
    // K (L,H) in 1MB of d_ws.
    float* KT   = (float*)d_out;
    float* Kbuf = (float*)d_ws;

    ssm_prep_kernel<<<dim3(SSM_H), dim3(256), 0, stream>>>(As, Bsin, Csin, lsteps, KT);
    ssm_ktr_kernel<<<dim3(256), dim3(256), 0, stream>>>(KT, Kbuf);
    ssm_conv_kernel<<<dim3(512), dim3(128), 0, stream>>>(inp, Kbuf, Dsin, Y);
}